// Round 6
// baseline (5700.604 us; speedup 1.0000x reference)
//
#include <hip/hip_runtime.h>

typedef unsigned short u16;
typedef unsigned int u32;
typedef __attribute__((ext_vector_type(4))) float f32x4;
typedef __attribute__((ext_vector_type(8))) short s16x8;
typedef __attribute__((ext_vector_type(2))) int i32x2;

#define B_ 64
#define T_ 512
#define E_ 1024
#define H_ 1024
#define HE_ 2048
#define N4_ 4096   // 4*H

__device__ __forceinline__ u16 f32_bf16(float f) {
  union { float f; u32 u; } v; v.f = f;
  u32 r = v.u + 0x7FFFu + ((v.u >> 16) & 1u);
  return (u16)(r >> 16);
}
__device__ __forceinline__ float bf16_f32(u16 h) {
  union { u32 u; float f; } v; v.u = ((u32)h) << 16;
  return v.f;
}
__device__ __forceinline__ void async16(void* lds, const void* g) {
  __builtin_amdgcn_global_load_lds(
      (const __attribute__((address_space(1))) void*)g,
      (__attribute__((address_space(3))) void*)lds, 16, 0, 0);
}
__device__ __forceinline__ float sigmoidf_(float x) {
  return 1.0f / (1.0f + __expf(-x));
}
// coherent (LLC-direct, bypass L1+L2) accesses for cross-WG a-buffers
__device__ __forceinline__ s16x8 load16_cc(const u16* p) {
  s16x8 r;
  asm volatile("global_load_dwordx4 %0, %1, off sc0 sc1"
               : "=v"(r) : "v"(p) : "memory");
  return r;
}
__device__ __forceinline__ void store2_cc(u16* p, u16 v) {
  asm volatile("global_store_short %0, %1, off sc0 sc1"
               :: "v"(p), "v"((u32)v) : "memory");
}

// ---------------- fp32 -> bf16 bulk convert (4 elems/thread) ----------------
__global__ __launch_bounds__(256) void cvt4(const float* __restrict__ s,
                                            u16* __restrict__ d, int n4) {
  int i = blockIdx.x * 256 + threadIdx.x;
  if (i < n4) {
    float4 v = ((const float4*)s)[i];
    u16 o0 = f32_bf16(v.x), o1 = f32_bf16(v.y), o2 = f32_bf16(v.z), o3 = f32_bf16(v.w);
    ushort4 o; o.x = o0; o.y = o1; o.z = o2; o.w = o3;
    ((ushort4*)d)[i] = o;
  }
}

// ---------------- init: a0->bf16, bias concat, barrier reset ----------------
__global__ __launch_bounds__(256) void init_k(const float* __restrict__ a0,
                                              const float* __restrict__ bc,
                                              const float* __restrict__ bu,
                                              const float* __restrict__ bf_,
                                              const float* __restrict__ bo,
                                              u16* __restrict__ abuf0,
                                              float* __restrict__ bias4,
                                              int* __restrict__ bar) {
  int i = blockIdx.x * 256 + threadIdx.x;   // 65536 threads
  abuf0[i] = f32_bf16(a0[i]);
  if (i < N4_) {
    int g = i >> 10, h = i & 1023;
    const float* bp = (g == 0) ? bc : (g == 1) ? bu : (g == 2) ? bf_ : bo;
    bias4[i] = bp[h];
  }
  if (i < 512) bar[i] = 0;   // re-zero flags every graph replay (4 grp x 128)
}

// ---------------- phase 1: P[t][b][n] = bf16( X @ WxT + bias ) ----------------
// (unchanged from verified baseline)
__global__ __launch_bounds__(256) void gemm_p1(const u16* __restrict__ Xbf,
                                               const u16* __restrict__ Wbf,
                                               const float* __restrict__ bias4,
                                               u16* __restrict__ P) {
  __shared__ __align__(16) u16 As[128 * 64];
  __shared__ __align__(16) u16 Bs[128 * 64];
  int tid = threadIdx.x;
  int wid = tid >> 6, lane = tid & 63;
  int lane15 = lane & 15, quad = lane >> 4;
  int m0 = blockIdx.y * 128, n0 = blockIdx.x * 128;
  int wm = (wid >> 1) * 64, wn = (wid & 1) * 64;

  f32x4 acc[4][4] = {};

  for (int kc = 0; kc < 1024; kc += 64) {
    __syncthreads();
    for (int i = 0; i < 8; ++i) {
      int c = wid * 8 + i;
      int o = c * 1024 + lane * 16;
      int e = (o & 16383) >> 1;
      int row = e >> 6, kcol = e & 63;
      if (o < 16384) {
        async16((char*)As + c * 1024,
                Xbf + (size_t)(m0 + row) * 1024 + kc + kcol);
      } else {
        async16((char*)Bs + (c - 16) * 1024,
                Wbf + (size_t)(n0 + row) * 2048 + 1024 + kc + kcol);
      }
    }
    __syncthreads();
    for (int s = 0; s < 2; ++s) {
      s16x8 bfrag[4], afrag[4];
      for (int ni = 0; ni < 4; ++ni)
        bfrag[ni] = *(const s16x8*)&Bs[(wn + ni * 16 + lane15) * 64 + s * 32 + quad * 8];
      for (int mi = 0; mi < 4; ++mi)
        afrag[mi] = *(const s16x8*)&As[(wm + mi * 16 + lane15) * 64 + s * 32 + quad * 8];
      for (int mi = 0; mi < 4; ++mi)
        for (int ni = 0; ni < 4; ++ni)
          acc[mi][ni] = __builtin_amdgcn_mfma_f32_16x16x32_bf16(
              afrag[mi], bfrag[ni], acc[mi][ni], 0, 0, 0);
    }
  }
  for (int mi = 0; mi < 4; ++mi) {
    int mbase = m0 + wm + mi * 16 + quad * 4;
    for (int ni = 0; ni < 4; ++ni) {
      int n = n0 + wn + ni * 16 + lane15;
      float bv = bias4[n];
      for (int r = 0; r < 4; ++r) {
        int m = mbase + r;
        int b = m >> 9, t = m & 511;
        float v = acc[mi][ni][r] + bv;
        P[(size_t)(t * 64 + b) * N4_ + n] = f32_bf16(v);
      }
    }
  }
}

// ---------------- phase 2: PERSISTENT scan, 4 groups x 128 WGs, 2 WGs/CU ------
// Grid 512 WGs = 2/CU (co-resident capacity: LDS 72.5KB x2 = 145KB < 160KB,
// 8 waves/CU). Group grp = blockIdx>>7 owns batch rows [grp*16, grp*16+16);
// groups are independent recurrences -> co-resident WG pairs (mostly from
// DIFFERENT groups) interleave: one chain computes while the other spins on
// its barrier, hiding the LLC round-trip chain that R5's counters showed
// (VALU 6%, Mfma 4% = 90% waiting at 1 WG/CU).
// WG owns h-slice of 8 (W slice 4 gates x 8 h x 1024 k bf16 = 64KB, swizzled).
// Wave w owns k-quarter [256w,256w+256).
//   - fence-free coherence (R4): sc0 sc1 for a-buffers, relaxed flags,
//     release = vmcnt(0)+syncthreads, acquire = data-dep on poll.
//   - reduction: ONE syncthreads; partials in LDS [4][16][2][17] f32.
//   - poll: 128 flags via one dwordx2 per lane.
__global__ __launch_bounds__(256, 2) void scan_k(const u16* __restrict__ Wbf,
                                                 const u16* __restrict__ P,
                                                 const float* __restrict__ c0,
                                                 u16* __restrict__ ab0,
                                                 u16* __restrict__ ab1,
                                                 float* __restrict__ a_out,
                                                 float* __restrict__ out_aT,
                                                 float* __restrict__ out_cT,
                                                 int* __restrict__ bar) {
  // LDS: [0,65536) W swizzled (32 rows x 2048B) | [65536, +8704) f32 buf
  __shared__ __align__(16) char smem[65536 + 4 * 16 * 2 * 17 * 4];
  float* buf = (float*)(smem + 65536);

  const int tid = threadIdx.x;
  const int g = tid >> 6, lane = tid & 63;       // wave id = k-quarter
  const int lane15 = lane & 15, quad = lane >> 4;
  const int grp = blockIdx.x >> 7;                // batch group (0..3)
  const int hb  = blockIdx.x & 127;               // h-slice index (0..127)
  const int h0 = hb * 8;
  const int b0 = grp * 16;                        // group batch base
  const int kw0 = g * 256;                        // wave's k base (u16 idx)
  int* gbar = bar + grp * 128;                    // group's 128 flags

  // epilogue ownership (tid<128): b = b0 + (tid>>3), h = h0 + (tid&7)
  const int eb = tid >> 3, ehh = tid & 7;
  const int bg = b0 + (eb & 15);
  const bool epi = tid < 128;

  // ---- W slice -> LDS (XOR-swizzled: byte ^= (row&7)<<4), once ----
  for (int it = 0; it < 16; ++it) {
    int j = it * 256 + tid;                       // 16B chunk index, 4096 total
    int o = j * 16;
    int grow = o >> 11, kb = o & 2047;            // row (gate*8+hh), byte in row
    s16x8 v = *(const s16x8*)(Wbf +
        (size_t)((grow >> 3) * 1024 + h0 + (grow & 7)) * 2048 + (kb >> 1));
    *(s16x8*)(smem + ((grow << 11) | (kb ^ ((grow & 7) << 4)))) = v;
  }

  // ---- c0 -> reg (one (b,h) per epilogue thread) ----
  float c_reg = 0.f;
  u16 pc[4] = {0, 0, 0, 0};
  if (epi) {
    c_reg = c0[bg * 1024 + h0 + ehh];
#pragma unroll
    for (int ni = 0; ni < 4; ++ni)
      pc[ni] = P[(size_t)bg * N4_ + ni * 1024 + h0 + ehh];
  }
  __syncthreads();   // W in LDS visible

#pragma unroll 1
  for (int t = 0; t < T_; ++t) {
    const u16* ap = (t & 1) ? ab1 : ab0;
    u16* an = (t & 1) ? ab0 : ab1;

    // ---- A k-slice -> regs: 8 x dwordx4 sc0 sc1 (group's 16 rows) ----
    s16x8 abuf[8];
#pragma unroll
    for (int c = 0; c < 8; ++c)
      abuf[c] = load16_cc(ap + (size_t)(b0 + lane15) * 1024 +
                          kw0 + c * 32 + quad * 8);
    asm volatile("s_waitcnt vmcnt(0)" ::: "memory");
    __builtin_amdgcn_sched_barrier(0);   // rule #18: keep MFMAs below the wait

    // ---- 16 MFMA/wave (M=16 b, N=2 tiles of 16 (4g x 8h), K=256) ----
    f32x4 acc[2] = {};
#pragma unroll
    for (int c = 0; c < 8; ++c)
#pragma unroll
      for (int ni = 0; ni < 2; ++ni) {
        const int wrow = ni * 16 + lane15;
        s16x8 bfrag = *(const s16x8*)(smem + ((wrow << 11) |
            (((kw0 + c * 32 + quad * 8) * 2) ^ ((wrow & 7) << 4))));
        acc[ni] = __builtin_amdgcn_mfma_f32_16x16x32_bf16(
            abuf[c], bfrag, acc[ni], 0, 0, 0);
      }

    // ---- all wave-partials -> LDS, one sync ----
    // acc[ni][r] = C(b = quad*4+r, c32 = ni*16+lane15), c32 = gate*8+hh
#pragma unroll
    for (int ni = 0; ni < 2; ++ni)
#pragma unroll
      for (int r = 0; r < 4; ++r)
        buf[((g * 16 + quad * 4 + r) * 2 + ni) * 17 + lane15] = acc[ni][r];
    __syncthreads();

    float a1 = 0.f, c1 = 0.f;
    if (epi) {
      // ---- fused epilogue: sum 4 k-partials/gate + P -> gates -> c,a ----
      float s[4];
#pragma unroll
      for (int gate = 0; gate < 4; ++gate) {
        int c32 = gate * 8 + ehh, ni = c32 >> 4, cc = c32 & 15;
        float acc_s = 0.f;
#pragma unroll
        for (int w = 0; w < 4; ++w)
          acc_s += buf[((w * 16 + eb) * 2 + ni) * 17 + cc];
        s[gate] = acc_s + bf16_f32(pc[gate]);
      }
      float cand = tanhf(s[0]);
      float uu   = sigmoidf_(s[1]);
      float ff   = sigmoidf_(s[2]);
      float oo   = sigmoidf_(s[3]);
      c1 = uu * cand + ff * c_reg;
      c_reg = c1;
      a1 = oo * tanhf(c1);
    }

    if (t < T_ - 1) {
      // ---- release: a_next (sc0 sc1) -> wait -> sync -> flag ----
      if (epi) store2_cc(an + bg * 1024 + h0 + ehh, f32_bf16(a1));
      asm volatile("s_waitcnt vmcnt(0)" ::: "memory");
      __syncthreads();                 // all an-stores acked
      if (tid == 0)
        __hip_atomic_store(&gbar[hb], t + 1, __ATOMIC_RELAXED,
                           __HIP_MEMORY_SCOPE_AGENT);
      if (epi) {
        // outputs + P prefetch for t+1 overlap flag propagation
        a_out[((size_t)bg * T_ + t) * H_ + h0 + ehh] = a1;
        const u16* Pt = P + (size_t)(t + 1) * 64 * N4_ + (size_t)bg * N4_ +
                        h0 + ehh;
#pragma unroll
        for (int ni = 0; ni < 4; ++ni)
          pc[ni] = Pt[ni * 1024];
      }
      // ---- every wave polls the group's 128 flags (2/lane, one dwordx2) ----
      while (true) {
        i32x2 v;
        asm volatile("global_load_dwordx2 %0, %1, off sc0 sc1\n\t"
                     "s_waitcnt vmcnt(0)"
                     : "=&v"(v) : "v"(gbar + lane * 2) : "memory");
        if (__all(v[0] > t && v[1] > t)) break;
        __builtin_amdgcn_s_sleep(1);
      }
    } else if (epi) {
      a_out[((size_t)bg * T_ + t) * H_ + h0 + ehh] = a1;
      out_aT[bg * 1024 + h0 + ehh] = a1;
      out_cT[bg * 1024 + h0 + ehh] = c1;
    }
  }
}

extern "C" void kernel_launch(void* const* d_in, const int* in_sizes, int n_in,
                              void* d_out, int out_size, void* d_ws, size_t ws_size,
                              hipStream_t stream) {
  const float* x_i = (const float*)d_in[0];
  const float* a0  = (const float*)d_in[1];
  const float* c0  = (const float*)d_in[2];
  const float* w[4] = {(const float*)d_in[3], (const float*)d_in[4],
                       (const float*)d_in[5], (const float*)d_in[6]};
  const float* bb[4] = {(const float*)d_in[7], (const float*)d_in[8],
                        (const float*)d_in[9], (const float*)d_in[10]};
  float* out = (float*)d_out;

  char* ws = (char*)d_ws;
  u16* Wbf   = (u16*)ws;                          // 16,777,216 B
  u16* Xbf   = (u16*)(ws + 16777216);             // 67,108,864 B
  u16* P     = (u16*)(ws + 83886080);             // 268,435,456 B
  float* bias4 = (float*)(ws + 352321536);        // 16,384 B
  u16* abuf0 = (u16*)(ws + 352337920);            // 131,072 B
  u16* abuf1 = (u16*)(ws + 352468992);            // 131,072 B
  int* bar   = (int*)(ws + 352600064);            // 2,048 B

  for (int g = 0; g < 4; ++g)
    cvt4<<<2048, 256, 0, stream>>>(w[g], Wbf + (size_t)g * 1024 * 2048, 524288);
  cvt4<<<32768, 256, 0, stream>>>(x_i, Xbf, 8388608);
  init_k<<<256, 256, 0, stream>>>(a0, bb[0], bb[1], bb[2], bb[3],
                                  abuf0, bias4, bar);
  gemm_p1<<<dim3(32, 256), 256, 0, stream>>>(Xbf, Wbf, bias4, P);
  // phase 2: 4 groups x 128 h-split WGs, 2 WGs/CU -> interleaved chains
  scan_k<<<512, 256, 0, stream>>>(Wbf, P, c0, abuf0, abuf1,
                                  out, out + 33554432, out + 33619968, bar);
}

// Round 7
// 2609.030 us; speedup vs baseline: 2.1850x; 2.1850x over previous
//
#include <hip/hip_runtime.h>

typedef unsigned short u16;
typedef unsigned int u32;
typedef __attribute__((ext_vector_type(4))) float f32x4;
typedef __attribute__((ext_vector_type(8))) short s16x8;

#define B_ 64
#define T_ 512
#define E_ 1024
#define H_ 1024
#define HE_ 2048
#define N4_ 4096   // 4*H

__device__ __forceinline__ u16 f32_bf16(float f) {
  union { float f; u32 u; } v; v.f = f;
  u32 r = v.u + 0x7FFFu + ((v.u >> 16) & 1u);
  return (u16)(r >> 16);
}
__device__ __forceinline__ float bf16_f32(u16 h) {
  union { u32 u; float f; } v; v.u = ((u32)h) << 16;
  return v.f;
}
__device__ __forceinline__ void async16(void* lds, const void* g) {
  __builtin_amdgcn_global_load_lds(
      (const __attribute__((address_space(1))) void*)g,
      (__attribute__((address_space(3))) void*)lds, 16, 0, 0);
}
__device__ __forceinline__ float sigmoidf_(float x) {
  return 1.0f / (1.0f + __expf(-x));
}
// coherent (LLC-direct, bypass L1+L2) accesses for cross-WG a-buffers
__device__ __forceinline__ s16x8 load16_cc(const u16* p) {
  s16x8 r;
  asm volatile("global_load_dwordx4 %0, %1, off sc0 sc1"
               : "=v"(r) : "v"(p) : "memory");
  return r;
}
__device__ __forceinline__ void store2_cc(u16* p, u16 v) {
  asm volatile("global_store_short %0, %1, off sc0 sc1"
               :: "v"(p), "v"((u32)v) : "memory");
}

// ---------------- fp32 -> bf16 bulk convert (4 elems/thread) ----------------
__global__ __launch_bounds__(256) void cvt4(const float* __restrict__ s,
                                            u16* __restrict__ d, int n4) {
  int i = blockIdx.x * 256 + threadIdx.x;
  if (i < n4) {
    float4 v = ((const float4*)s)[i];
    u16 o0 = f32_bf16(v.x), o1 = f32_bf16(v.y), o2 = f32_bf16(v.z), o3 = f32_bf16(v.w);
    ushort4 o; o.x = o0; o.y = o1; o.z = o2; o.w = o3;
    ((ushort4*)d)[i] = o;
  }
}

// ---------------- init: a0->bf16, bias concat, barrier reset ----------------
__global__ __launch_bounds__(256) void init_k(const float* __restrict__ a0,
                                              const float* __restrict__ bc,
                                              const float* __restrict__ bu,
                                              const float* __restrict__ bf_,
                                              const float* __restrict__ bo,
                                              u16* __restrict__ abuf0,
                                              float* __restrict__ bias4,
                                              int* __restrict__ bar) {
  int i = blockIdx.x * 256 + threadIdx.x;   // 65536 threads
  abuf0[i] = f32_bf16(a0[i]);
  if (i < N4_) {
    int g = i >> 10, h = i & 1023;
    const float* bp = (g == 0) ? bc : (g == 1) ? bu : (g == 2) ? bf_ : bo;
    bias4[i] = bp[h];
  }
  if (i < 512) bar[i] = 0;   // re-zero flags every graph replay (4 grp x 64)
}

// ---------------- phase 1: P = bf16( X @ WxT + bias ) ----------------
// P layout: [t][hb][b][gate][eh]  (hb = h>>4, eh = h&15) -> each scan WG's
// per-step tile (16 b x 4 gates x 16 h) is 2 KB CONTIGUOUS (zero overfetch).
__global__ __launch_bounds__(256) void gemm_p1(const u16* __restrict__ Xbf,
                                               const u16* __restrict__ Wbf,
                                               const float* __restrict__ bias4,
                                               u16* __restrict__ P) {
  __shared__ __align__(16) u16 As[128 * 64];
  __shared__ __align__(16) u16 Bs[128 * 64];
  int tid = threadIdx.x;
  int wid = tid >> 6, lane = tid & 63;
  int lane15 = lane & 15, quad = lane >> 4;
  int m0 = blockIdx.y * 128, n0 = blockIdx.x * 128;
  int wm = (wid >> 1) * 64, wn = (wid & 1) * 64;

  f32x4 acc[4][4] = {};

  for (int kc = 0; kc < 1024; kc += 64) {
    __syncthreads();
    for (int i = 0; i < 8; ++i) {
      int c = wid * 8 + i;
      int o = c * 1024 + lane * 16;
      int e = (o & 16383) >> 1;
      int row = e >> 6, kcol = e & 63;
      if (o < 16384) {
        async16((char*)As + c * 1024,
                Xbf + (size_t)(m0 + row) * 1024 + kc + kcol);
      } else {
        async16((char*)Bs + (c - 16) * 1024,
                Wbf + (size_t)(n0 + row) * 2048 + 1024 + kc + kcol);
      }
    }
    __syncthreads();
    for (int s = 0; s < 2; ++s) {
      s16x8 bfrag[4], afrag[4];
      for (int ni = 0; ni < 4; ++ni)
        bfrag[ni] = *(const s16x8*)&Bs[(wn + ni * 16 + lane15) * 64 + s * 32 + quad * 8];
      for (int mi = 0; mi < 4; ++mi)
        afrag[mi] = *(const s16x8*)&As[(wm + mi * 16 + lane15) * 64 + s * 32 + quad * 8];
      for (int mi = 0; mi < 4; ++mi)
        for (int ni = 0; ni < 4; ++ni)
          acc[mi][ni] = __builtin_amdgcn_mfma_f32_16x16x32_bf16(
              afrag[mi], bfrag[ni], acc[mi][ni], 0, 0, 0);
    }
  }
  for (int mi = 0; mi < 4; ++mi) {
    int mbase = m0 + wm + mi * 16 + quad * 4;
    for (int ni = 0; ni < 4; ++ni) {
      int n = n0 + wn + ni * 16 + lane15;
      int gate = n >> 10, h = n & 1023;
      int hbp = h >> 4, eh = h & 15;
      float bv = bias4[n];
      for (int r = 0; r < 4; ++r) {
        int m = mbase + r;
        int b = m >> 9, t = m & 511;
        float v = acc[mi][ni][r] + bv;
        P[(((size_t)t * 64 + hbp) << 12) + b * 64 + gate * 16 + eh] = f32_bf16(v);
      }
    }
  }
}

// ---------------- phase 2: PERSISTENT scan, dependency-exact wave sync --------
// R5 geometry: 256 WGs = 1/CU; group grp = blockIdx>>6 owns batch rows
// [grp*16,grp*16+16); WG hb owns h-slice [hb*16,hb*16+16); wave w owns
// k-quarter [256w,256w+256).
// NEW: no group-wide barrier. Wave g's k-quarter of a_prev is produced by
// exactly 16 WGs (hb' in [16g,16g+16)) -> wave g polls ONLY those 16 flags
// (one 64B line, one request) and proceeds. The reduction __syncthreads joins
// the 4 waves (whose producer sets union to all 64) BEFORE the a_next stores,
// so 2-buffer ping-pong stays safe: flag>=t+1 => that WG finished reading
// buf[t&1]; all 64 observed >= t+1 before we overwrite buf[t&1] at t+1.
//   - fence-free coherence (R4): sc0 sc1 a-buffers, relaxed flags,
//     release = vmcnt(0)+syncthreads+flag, acquire = data-dep on poll.
__global__ __launch_bounds__(256, 1) void scan_k(const u16* __restrict__ Wbf,
                                                 const u16* __restrict__ P,
                                                 const float* __restrict__ c0,
                                                 u16* __restrict__ ab0,
                                                 u16* __restrict__ ab1,
                                                 float* __restrict__ a_out,
                                                 float* __restrict__ out_aT,
                                                 float* __restrict__ out_cT,
                                                 int* __restrict__ bar) {
  // LDS: [0,131072) W swizzled | [131072, +16896) f32 buf [64][66]
  __shared__ __align__(16) char smem[131072 + 64 * 66 * 4];
  float* buf = (float*)(smem + 131072);

  const int tid = threadIdx.x;
  const int g = tid >> 6, lane = tid & 63;       // wave id = k-quarter
  const int lane15 = lane & 15, quad = lane >> 4;
  const int grp = blockIdx.x >> 6;                // batch group (0..3)
  const int hb  = blockIdx.x & 63;                // h-slice index (0..63)
  const int h0 = hb * 16;
  const int b0 = grp * 16;                        // group batch base
  const int kw0 = g * 256;                        // wave's k base (u16 idx)
  int* gbar = bar + grp * 64;                     // group's 64 flags
  const int pidx = (g << 4) + lane15;             // wave g's producer flag idx

  // epilogue ownership: thread -> (b = b0 + (tid>>4), h = h0 + (tid&15))
  const int eb = tid >> 4, ehh = tid & 15;
  const int bg = b0 + eb;

  // ---- W slice -> LDS (XOR-swizzled: byte ^= (row&7)<<4), once ----
  for (int it = 0; it < 32; ++it) {
    int j = it * 256 + tid;                       // 16B chunk index, 8192 total
    int o = j * 16;
    int grow = o >> 11, kb = o & 2047;            // row (gate*16+hh), byte in row
    s16x8 v = *(const s16x8*)(Wbf +
        (size_t)((grow >> 4) * 1024 + h0 + (grow & 15)) * 2048 + (kb >> 1));
    *(s16x8*)(smem + ((grow << 11) | (kb ^ ((grow & 7) << 4)))) = v;
  }

  // ---- c0 -> reg; P(t=0) prefetch (new layout: 2KB contiguous per WG) ----
  float c_reg = c0[bg * 1024 + h0 + ehh];
  u16 pc[4];
  {
    const u16* Pt = P + ((size_t)hb << 12) + bg * 64 + ehh;
#pragma unroll
    for (int ni = 0; ni < 4; ++ni)
      pc[ni] = Pt[ni * 16];
  }
  __syncthreads();   // W in LDS visible

#pragma unroll 1
  for (int t = 0; t < T_; ++t) {
    const u16* ap = (t & 1) ? ab1 : ab0;
    u16* an = (t & 1) ? ab0 : ab1;

    // ---- dependency-exact poll: wave g waits on its 16 producers only ----
    if (t > 0) {
      while (true) {
        int v;
        asm volatile("global_load_dword %0, %1, off sc0 sc1\n\t"
                     "s_waitcnt vmcnt(0)"
                     : "=&v"(v) : "v"(gbar + pidx) : "memory");
        if (__all(v >= t)) break;
        __builtin_amdgcn_s_sleep(1);
      }
    }

    // ---- A k-slice -> regs: 8 x dwordx4 sc0 sc1 (group's 16 rows) ----
    s16x8 abuf[8];
#pragma unroll
    for (int c = 0; c < 8; ++c)
      abuf[c] = load16_cc(ap + (size_t)(b0 + lane15) * 1024 +
                          kw0 + c * 32 + quad * 8);
    asm volatile("s_waitcnt vmcnt(0)" ::: "memory");
    __builtin_amdgcn_sched_barrier(0);   // rule #18: keep MFMAs below the wait

    // ---- 32 MFMA/wave (M=16 rows, N=4 gate-tiles, K=256) ----
    f32x4 acc[4] = {};
#pragma unroll
    for (int c = 0; c < 8; ++c)
#pragma unroll
      for (int ni = 0; ni < 4; ++ni) {
        const int wrow = ni * 16 + lane15;
        s16x8 bfrag = *(const s16x8*)(smem + ((wrow << 11) |
            (((kw0 + c * 32 + quad * 8) * 2) ^ ((wrow & 7) << 4))));
        acc[ni] = __builtin_amdgcn_mfma_f32_16x16x32_bf16(
            abuf[c], bfrag, acc[ni], 0, 0, 0);
      }

    // ---- all 4 wave-partials -> LDS, one sync (joins the 4 waves) ----
#pragma unroll
    for (int ni = 0; ni < 4; ++ni)
#pragma unroll
      for (int r = 0; r < 4; ++r)
        buf[(g * 16 + quad * 4 + r) * 66 + ni * 16 + lane15] = acc[ni][r];
    __syncthreads();

    // ---- fused epilogue: sum 4 partials/gate + P -> gates -> c,a ----
    float s0 = 0.f, s1 = 0.f, s2 = 0.f, s3 = 0.f;
#pragma unroll
    for (int w = 0; w < 4; ++w) {
      int base = (w * 16 + eb) * 66 + ehh;
      s0 += buf[base];
      s1 += buf[base + 16];
      s2 += buf[base + 32];
      s3 += buf[base + 48];
    }
    float cand = tanhf(s0 + bf16_f32(pc[0]));
    float uu   = sigmoidf_(s1 + bf16_f32(pc[1]));
    float ff   = sigmoidf_(s2 + bf16_f32(pc[2]));
    float oo   = sigmoidf_(s3 + bf16_f32(pc[3]));
    float c1 = uu * cand + ff * c_reg;
    c_reg = c1;
    float a1 = oo * tanhf(c1);

    if (t < T_ - 1) {
      // ---- release: a_next (sc0 sc1) -> wait -> sync -> flag ----
      store2_cc(an + bg * 1024 + h0 + ehh, f32_bf16(a1));
      asm volatile("s_waitcnt vmcnt(0)" ::: "memory");
      __syncthreads();                 // all an-stores acked
      if (tid == 0)
        __hip_atomic_store(&gbar[hb], t + 1, __ATOMIC_RELAXED,
                           __HIP_MEMORY_SCOPE_AGENT);
      // outputs + P prefetch for t+1 overlap producer stragglers
      a_out[((size_t)bg * T_ + t) * H_ + h0 + ehh] = a1;
      {
        const u16* Pt = P + (((size_t)(t + 1) * 64 + hb) << 12) + bg * 64 + ehh;
#pragma unroll
        for (int ni = 0; ni < 4; ++ni)
          pc[ni] = Pt[ni * 16];
      }
    } else {
      a_out[((size_t)bg * T_ + t) * H_ + h0 + ehh] = a1;
      out_aT[bg * 1024 + h0 + ehh] = a1;
      out_cT[bg * 1024 + h0 + ehh] = c1;
    }
  }
}

extern "C" void kernel_launch(void* const* d_in, const int* in_sizes, int n_in,
                              void* d_out, int out_size, void* d_ws, size_t ws_size,
                              hipStream_t stream) {
  const float* x_i = (const float*)d_in[0];
  const float* a0  = (const float*)d_in[1];
  const float* c0  = (const float*)d_in[2];
  const float* w[4] = {(const float*)d_in[3], (const float*)d_in[4],
                       (const float*)d_in[5], (const float*)d_in[6]};
  const float* bb[4] = {(const float*)d_in[7], (const float*)d_in[8],
                        (const float*)d_in[9], (const float*)d_in[10]};
  float* out = (float*)d_out;

  char* ws = (char*)d_ws;
  u16* Wbf   = (u16*)ws;                          // 16,777,216 B
  u16* Xbf   = (u16*)(ws + 16777216);             // 67,108,864 B
  u16* P     = (u16*)(ws + 83886080);             // 268,435,456 B
  float* bias4 = (float*)(ws + 352321536);        // 16,384 B
  u16* abuf0 = (u16*)(ws + 352337920);            // 131,072 B
  u16* abuf1 = (u16*)(ws + 352468992);            // 131,072 B
  int* bar   = (int*)(ws + 352600064);            // 2,048 B

  for (int g = 0; g < 4; ++g)
    cvt4<<<2048, 256, 0, stream>>>(w[g], Wbf + (size_t)g * 1024 * 2048, 524288);
  cvt4<<<32768, 256, 0, stream>>>(x_i, Xbf, 8388608);
  init_k<<<256, 256, 0, stream>>>(a0, bb[0], bb[1], bb[2], bb[3],
                                  abuf0, bias4, bar);
  gemm_p1<<<dim3(32, 256), 256, 0, stream>>>(Xbf, Wbf, bias4, P);
  // phase 2: 4 groups x 64 WGs, 1 WG/CU, dependency-exact per-wave sync
  scan_k<<<256, 256, 0, stream>>>(Wbf, P, c0, abuf0, abuf1,
                                  out, out + 33554432, out + 33619968, bar);
}